// Round 23
// baseline (257.681 us; speedup 1.0000x reference)
//
#include <hip/hip_runtime.h>
#include <hip/hip_cooperative_groups.h>
#include <math.h>

namespace cg = cooperative_groups;

// keypoints [B,3,M] f32, pc [B,3,N] f32.
#define BATCH 4
#define M 1024
#define N 32768
#define MG 16                      // keypoints per block
#define NMG (M / MG)               // 64
#define CSPLIT 8                   // chunks of N
#define NPC (N / CSPLIT)           // 4096 points per block
#define TPB 128                    // 2 waves/block -> 8 blocks/CU co-resident
#define ROWS (BATCH * M)           // 4096
#define GRID (BATCH * NMG * CSPLIT) // 2048

// ws: pmin[ROWS][CSPLIT] = 128 KB, every cell written once per iteration.
// Single cooperative dispatch: main phase -> grid.sync -> block 0 tail.
// R21 post-mortem: 2-dispatch structure converged at ~70-72us; last
// structural lever is killing the inter-dispatch gap.
__global__ __launch_bounds__(TPB) void p2p_fused(
        const float* __restrict__ kp, const float* __restrict__ pc,
        float* __restrict__ pmin, float* __restrict__ out) {
    const int c  = blockIdx.x & (CSPLIT - 1);
    const int mg = (blockIdx.x >> 3) & (NMG - 1);
    const int b  = blockIdx.x >> 9;
    const int t  = threadIdx.x;

    // Block-uniform keypoint loads -> scalar registers.
    const float* kpb = kp + (size_t)b * 3 * M + mg * MG;
    float skx[MG], sky[MG], skz[MG];
#pragma unroll
    for (int k = 0; k < MG; ++k) {
        skx[k] = kpb[k];
        sky[k] = kpb[M + k];
        skz[k] = kpb[2 * M + k];
    }

    float mq[MG];
#pragma unroll
    for (int k = 0; k < MG; ++k) mq[k] = -INFINITY;

    // Each thread: 32 points as 8 float4-triplets, coalesced across block.
    const float* pcb = pc + (size_t)b * 3 * N + c * NPC;
#pragma unroll 2
    for (int g = 0; g < NPC / (TPB * 4); ++g) {   // 8 iterations
        const int n = g * (TPB * 4) + t * 4;
        float4 X4 = *(const float4*)&pcb[n];
        float4 Y4 = *(const float4*)&pcb[N + n];
        float4 Z4 = *(const float4*)&pcb[2 * N + n];
        float xs[4] = {X4.x, X4.y, X4.z, X4.w};
        float ys[4] = {Y4.x, Y4.y, Y4.z, Y4.w};
        float zs[4] = {Z4.x, Z4.y, Z4.z, Z4.w};
        float w[4];
#pragma unroll
        for (int p = 0; p < 4; ++p)
            w[p] = -0.5f * fmaf(xs[p], xs[p],
                                fmaf(ys[p], ys[p], zs[p] * zs[p]));
#pragma unroll
        for (int k = 0; k < MG; ++k) {
            float q0 = fmaf(skz[k], zs[0], fmaf(sky[k], ys[0],
                        fmaf(skx[k], xs[0], w[0])));
            float q1 = fmaf(skz[k], zs[1], fmaf(sky[k], ys[1],
                        fmaf(skx[k], xs[1], w[1])));
            float q2 = fmaf(skz[k], zs[2], fmaf(sky[k], ys[2],
                        fmaf(skx[k], xs[2], w[2])));
            float q3 = fmaf(skz[k], zs[3], fmaf(sky[k], ys[3],
                        fmaf(skx[k], xs[3], w[3])));
            // fmaxf chains fuse to v_max3_f32
            mq[k] = fmaxf(fmaxf(mq[k], q0), q1);
            mq[k] = fmaxf(fmaxf(mq[k], q2), q3);
        }
    }

    // Block max-reduce per keypoint row: [16 rows][128 lanes] LDS tree.
    __shared__ float smax[MG][TPB + 1];     // +1 pad
    __shared__ float s2[MG][9];
#pragma unroll
    for (int k = 0; k < MG; ++k) smax[k][t] = mq[k];
    __syncthreads();
    {
        const int r = t >> 3, s = t & 7;    // 16 rows x 8 segments of 16
        float m = smax[r][s * 16];
#pragma unroll
        for (int j = 1; j < 16; ++j) m = fmaxf(m, smax[r][s * 16 + j]);
        s2[r][s] = m;
    }
    __syncthreads();
    if (t < MG) {
        float m = s2[t][0];
#pragma unroll
        for (int j = 1; j < 8; ++j) m = fmaxf(m, s2[t][j]);
        float kx = kpb[t], ky = kpb[M + t], kz = kpb[2 * M + t];
        float k2 = fmaf(kx, kx, fmaf(ky, ky, kz * kz));
        float d2 = fmaxf(fmaf(-2.0f, m, k2), 0.0f);  // clamp >= 0
        pmin[(size_t)(b * M + mg * MG + t) * CSPLIT + c] = d2;
    }

    // Grid-wide barrier (includes device-scope release of the pmin stores).
    cg::this_grid().sync();

    // Tail: block 0 only. 128 threads x 32 rows; agent-scope loads for
    // cross-XCD visibility of other blocks' pmin stores.
    if (blockIdx.x == 0) {
        __shared__ float sb[2];
        float s = 0.f;
#pragma unroll 4
        for (int i = 0; i < ROWS / TPB; ++i) {     // 32 rows/thread
            int r = i * TPB + t;
            const float* prow = pmin + (size_t)r * CSPLIT;
            float v = INFINITY;
#pragma unroll
            for (int j = 0; j < CSPLIT; ++j) {
                float u = __hip_atomic_load(&prow[j], __ATOMIC_RELAXED,
                                            __HIP_MEMORY_SCOPE_AGENT);
                v = fminf(v, u);
            }
            s += sqrtf(v);
        }
#pragma unroll
        for (int off = 32; off > 0; off >>= 1) s += __shfl_down(s, off, 64);
        if ((t & 63) == 0) sb[t >> 6] = s;
        __syncthreads();
        if (t == 0) out[0] = (sb[0] + sb[1]) / (float)ROWS;
    }
}

extern "C" void kernel_launch(void* const* d_in, const int* in_sizes, int n_in,
                              void* d_out, int out_size, void* d_ws, size_t ws_size,
                              hipStream_t stream) {
    const float* kp = (const float*)d_in[0];   // [B,3,M]
    const float* pc = (const float*)d_in[1];   // [B,3,N]
    float* out = (float*)d_out;
    float* pmin = (float*)d_ws;                // 128 KB

    void* args[] = {(void*)&kp, (void*)&pc, (void*)&pmin, (void*)&out};
    hipLaunchCooperativeKernel((const void*)p2p_fused, dim3(GRID), dim3(TPB),
                               args, 0, stream);
}

// Round 24
// 71.054 us; speedup vs baseline: 3.6265x; 3.6265x over previous
//
#include <hip/hip_runtime.h>
#include <math.h>

// keypoints [B,3,M] f32, pc [B,3,N] f32.
#define BATCH 4
#define M 1024
#define N 32768
#define MG 16                      // keypoints per block (SGPR-resident)
#define NMG (M / MG)               // 64 keypoint-groups per batch
#define CSPLIT 8                   // 2048 blocks = 8 blocks/CU
#define NPC (N / CSPLIT)           // 4096 points per block
#define TPB 256
#define ROWS (BATCH * M)           // 4096

// ws: pmin[CSPLIT][ROWS] floats = 128 KB. Every cell written exactly once by
// K1 (no init vs poison needed); K2 combines. No atomics anywhere.
//
// BEST MEASURED: this exact kernel = 70.34us (R15). Falsified variants:
//  - readfirstlane+launch_bounds(,8): 71.8 (R16)
//  - transposed pmin[ROWS][CSPLIT]:   72.1 (R21)
//  - cooperative single-dispatch:    257.7 (R23 - grid.sync ~170us on 8 XCDs)
// ~40.4us of the total is the harness poison-fill at 84% HBM peak (its
// roofline); our pipeline is ~30us incl. 2 dispatch overheads.
__global__ __launch_bounds__(TPB) void p2p_main(
        const float* __restrict__ kp, const float* __restrict__ pc,
        float* __restrict__ pmin) {
    const int c  = blockIdx.x & (CSPLIT - 1);
    const int mg = (blockIdx.x >> 3) & (NMG - 1);
    const int b  = blockIdx.x >> 9;
    const int t  = threadIdx.x;

    // Block-uniform keypoint loads -> scalar registers.
    const float* kpb = kp + (size_t)b * 3 * M + mg * MG;
    float skx[MG], sky[MG], skz[MG];
#pragma unroll
    for (int k = 0; k < MG; ++k) {
        skx[k] = kpb[k];
        sky[k] = kpb[M + k];
        skz[k] = kpb[2 * M + k];
    }

    float mq[MG];
#pragma unroll
    for (int k = 0; k < MG; ++k) mq[k] = -INFINITY;

    // Each thread: 16 points as 4 float4-triplets, coalesced across block.
    const float* pcb = pc + (size_t)b * 3 * N + c * NPC;
#pragma unroll 2
    for (int g = 0; g < NPC / (TPB * 4); ++g) {   // 4 iterations
        const int n = g * (TPB * 4) + t * 4;
        float4 X4 = *(const float4*)&pcb[n];
        float4 Y4 = *(const float4*)&pcb[N + n];
        float4 Z4 = *(const float4*)&pcb[2 * N + n];
        float xs[4] = {X4.x, X4.y, X4.z, X4.w};
        float ys[4] = {Y4.x, Y4.y, Y4.z, Y4.w};
        float zs[4] = {Z4.x, Z4.y, Z4.z, Z4.w};
        float w[4];
#pragma unroll
        for (int p = 0; p < 4; ++p)
            w[p] = -0.5f * fmaf(xs[p], xs[p],
                                fmaf(ys[p], ys[p], zs[p] * zs[p]));
#pragma unroll
        for (int k = 0; k < MG; ++k) {
            float q0 = fmaf(skz[k], zs[0], fmaf(sky[k], ys[0],
                        fmaf(skx[k], xs[0], w[0])));
            float q1 = fmaf(skz[k], zs[1], fmaf(sky[k], ys[1],
                        fmaf(skx[k], xs[1], w[1])));
            float q2 = fmaf(skz[k], zs[2], fmaf(sky[k], ys[2],
                        fmaf(skx[k], xs[2], w[2])));
            float q3 = fmaf(skz[k], zs[3], fmaf(sky[k], ys[3],
                        fmaf(skx[k], xs[3], w[3])));
            // fmaxf chains fuse to v_max3_f32
            mq[k] = fmaxf(fmaxf(mq[k], q0), q1);
            mq[k] = fmaxf(fmaxf(mq[k], q2), q3);
        }
    }

    // Block max-reduce per keypoint row: [16 rows][256 lanes] LDS tree.
    __shared__ float smax[MG][TPB + 1];     // +1 pad
    __shared__ float s2[MG][17];
#pragma unroll
    for (int k = 0; k < MG; ++k) smax[k][t] = mq[k];
    __syncthreads();
    {
        const int r = t >> 4, s = t & 15;   // 16 segments of 16 per row
        float m = smax[r][s * 16];
#pragma unroll
        for (int j = 1; j < 16; ++j) m = fmaxf(m, smax[r][s * 16 + j]);
        s2[r][s] = m;
    }
    __syncthreads();
    if (t < MG) {
        float m = s2[t][0];
#pragma unroll
        for (int j = 1; j < 16; ++j) m = fmaxf(m, s2[t][j]);
        // k2 per-lane (t = row): re-load this keypoint (L1-hot).
        float kx = kpb[t], ky = kpb[M + t], kz = kpb[2 * M + t];
        float k2 = fmaf(kx, kx, fmaf(ky, ky, kz * kz));
        float d2 = fmaxf(fmaf(-2.0f, m, k2), 0.0f);  // clamp >= 0
        pmin[(size_t)c * ROWS + b * M + mg * MG + t] = d2;
    }
}

// K2: combine CSPLIT partials per row, sqrt, mean. 1 block, deterministic.
__global__ __launch_bounds__(1024) void p2p_tail(
        const float* __restrict__ pmin, float* __restrict__ out) {
    __shared__ float sbuf[16];
    const int t = threadIdx.x;
    float s = 0.f;
#pragma unroll
    for (int i = 0; i < ROWS / 1024; ++i) {       // 4 rows per thread
        int r = i * 1024 + t;
        float v = pmin[r];
#pragma unroll
        for (int c2 = 1; c2 < CSPLIT; ++c2)
            v = fminf(v, pmin[(size_t)c2 * ROWS + r]);
        s += sqrtf(v);
    }
#pragma unroll
    for (int off = 32; off > 0; off >>= 1) s += __shfl_down(s, off, 64);
    if ((t & 63) == 0) sbuf[t >> 6] = s;
    __syncthreads();
    if (t == 0) {
        float tot = 0.f;
#pragma unroll
        for (int w = 0; w < 16; ++w) tot += sbuf[w];
        out[0] = tot / (float)ROWS;
    }
}

extern "C" void kernel_launch(void* const* d_in, const int* in_sizes, int n_in,
                              void* d_out, int out_size, void* d_ws, size_t ws_size,
                              hipStream_t stream) {
    const float* kp = (const float*)d_in[0];   // [B,3,M]
    const float* pc = (const float*)d_in[1];   // [B,3,N]
    float* out = (float*)d_out;
    float* pmin = (float*)d_ws;                // 128 KB

    p2p_main<<<BATCH * NMG * CSPLIT, TPB, 0, stream>>>(kp, pc, pmin);
    p2p_tail<<<1, 1024, 0, stream>>>(pmin, out);
}